// Round 1
// baseline (3620.458 us; speedup 1.0000x reference)
//
#include <hip/hip_runtime.h>
#include <hip/hip_bf16.h>

#define S3 3
#define BB 8
#define TT 48
#define NN 207
#define FF 256        // D_MODEL
#define DI 512        // D_INNER
#define DSN 16        // D_STATE
#define RR 16         // DT_RANK
#define LL 12
#define BN (BB*NN)    // 1656

__device__ __forceinline__ float fma4(float4 w, float4 v, float acc) {
    acc = fmaf(w.x, v.x, acc);
    acc = fmaf(w.y, v.y, acc);
    acc = fmaf(w.z, v.z, acc);
    acc = fmaf(w.w, v.w, acc);
    return acc;
}

// ---------------------------------------------------------------------------
// K1: per (scale, bn) sequence: in_proj -> conv+silu -> x_proj -> (dt_proj +
// scan fused) -> y  (y already includes *silu(z_last) and D*xc_last terms)
// ---------------------------------------------------------------------------
__global__ __launch_bounds__(256, 2)
void k1_seq(const float* __restrict__ x,
            const float* __restrict__ in_proj_w,
            const float* __restrict__ conv_w,
            const float* __restrict__ conv_b,
            const float* __restrict__ x_proj_w,
            const float* __restrict__ dt_proj_w,
            const float* __restrict__ dt_proj_b,
            const float* __restrict__ A_log,
            const float* __restrict__ Dw,
            float* __restrict__ ws_y)
{
    const int bn  = blockIdx.x;
    const int s   = blockIdx.y;
    const int tid = threadIdx.x;
    const int b   = bn / NN;
    const int n   = bn % NN;

    // LDS plan (75,776 B total -> 2 blocks/CU):
    //  sXZ [12][512] : xr, then xc (conv+silu in place)
    //  sWU           : phase A: W-tile [256][36 (32k+4 pad)]
    //                  phase C: x_proj_w tile [48][132]
    //                  phase E: dt_proj_w [512][17]
    //  sXA           : phase A: x_seq [12][256]; phase C+: x_dbl [12][48]
    //  sZ  [512]     : z at l=11
    __shared__ float sXZ[LL * DI];      // 6144 floats
    __shared__ float sWU[256 * 36];     // 9216 floats
    __shared__ float sXA[LL * FF];      // 3072 floats
    __shared__ float sZ[DI];            // 512 floats

    // ---- load x_seq (gather the scale's 12 time steps) ----
    const int t0 = (s == 0) ? 36 : (s == 1) ? 24 : 0;
    const int st = (s == 0) ? 1  : (s == 1) ? 2  : 4;
    for (int i = tid; i < LL * FF / 4; i += 256) {   // 768 float4
        int l  = i >> 6;            // 64 float4 per row
        int k4 = (i & 63) << 2;
        float4 v = *(const float4*)(x + (((size_t)b * TT + (t0 + l * st)) * NN + n) * FF + k4);
        *(float4*)&sXA[l * FF + k4] = v;
    }

    // ---- phase A: xz = x_seq @ in_proj_w^T  (e-tile 256, k-tile 32) ----
    // thread -> (eidx in [0,128), lg in {0,1}); e = e0+eidx, e0+eidx+128; l = lg*6+j
    const int eidx = tid & 127;
    const int lg   = tid >> 7;

    for (int et = 0; et < 4; ++et) {
        const int  e0  = et << 8;
        const bool isz = (et >= 2);            // e >= 512: z half, only l=11 needed
        float acc0[6] = {0.f,0.f,0.f,0.f,0.f,0.f};
        float acc1[6] = {0.f,0.f,0.f,0.f,0.f,0.f};

        for (int k0 = 0; k0 < 256; k0 += 32) {
            __syncthreads();
            // stage W[e0..e0+255][k0..k0+31], layout stride 36 (pad -> conflict-free)
            const float* wg = in_proj_w + ((size_t)s * 1024 + e0) * 256 + k0;
            #pragma unroll
            for (int j = 0; j < 8; ++j) {
                int idx = tid + (j << 8);       // float4 index 0..2047
                int row = idx >> 3;             // 8 float4 per row
                int k4  = (idx & 7) << 2;
                float4 w = *(const float4*)(wg + (size_t)row * 256 + k4);
                *(float4*)&sWU[row * 36 + k4] = w;
            }
            __syncthreads();

            if (!isz) {
                #pragma unroll
                for (int k4 = 0; k4 < 32; k4 += 4) {
                    float4 w0 = *(const float4*)&sWU[eidx * 36 + k4];
                    float4 w1 = *(const float4*)&sWU[(eidx + 128) * 36 + k4];
                    #pragma unroll
                    for (int j = 0; j < 6; ++j) {
                        float4 xv = *(const float4*)&sXA[(lg * 6 + j) * FF + k0 + k4];
                        acc0[j] = fma4(w0, xv, acc0[j]);
                        acc1[j] = fma4(w1, xv, acc1[j]);
                    }
                }
            } else {
                #pragma unroll
                for (int k4 = 0; k4 < 32; k4 += 4) {
                    float4 w0 = *(const float4*)&sWU[eidx * 36 + k4];
                    float4 w1 = *(const float4*)&sWU[(eidx + 128) * 36 + k4];
                    float4 xv = *(const float4*)&sXA[11 * FF + k0 + k4];
                    acc0[5] = fma4(w0, xv, acc0[5]);
                    acc1[5] = fma4(w1, xv, acc1[5]);
                }
            }
        }

        if (!isz) {
            #pragma unroll
            for (int j = 0; j < 6; ++j) {
                sXZ[(lg * 6 + j) * DI + e0 + eidx]       = acc0[j];
                sXZ[(lg * 6 + j) * DI + e0 + eidx + 128] = acc1[j];
            }
        } else if (lg == 0) {
            sZ[e0 - 512 + eidx]       = acc0[5];
            sZ[e0 - 512 + eidx + 128] = acc1[5];
        }
    }
    __syncthreads();

    // ---- phase B: causal conv4 + silu, in place per column ----
    for (int d = tid; d < DI; d += 256) {
        float4 cw = *(const float4*)(conv_w + ((size_t)s * DI + d) * 4);
        float  cb = conv_b[s * DI + d];
        float r[LL];
        #pragma unroll
        for (int l = 0; l < LL; ++l) r[l] = sXZ[l * DI + d];
        #pragma unroll
        for (int l = 0; l < LL; ++l) {
            float v = cb;
            if (l >= 3) v = fmaf(r[l - 3], cw.x, v);
            if (l >= 2) v = fmaf(r[l - 2], cw.y, v);
            if (l >= 1) v = fmaf(r[l - 1], cw.z, v);
            v = fmaf(r[l], cw.w, v);
            v = v / (1.0f + __expf(-v));        // silu
            sXZ[l * DI + d] = v;
        }
    }
    __syncthreads();

    // ---- phase C: x_dbl = xc @ x_proj_w^T  (12 x 48, K=512) ----
    const int cl = tid >> 4;      // 0..15 (valid < 12)
    const int og = tid & 15;      // 16 groups of 3 outputs
    float c0 = 0.f, c1 = 0.f, c2 = 0.f;
    for (int k0 = 0; k0 < 512; k0 += 128) {
        __syncthreads();
        // stage x_proj_w[0..47][k0..k0+127], stride 132
        #pragma unroll
        for (int j = 0; j < 6; ++j) {
            int idx = tid + (j << 8);           // float4 index 0..1535
            int row = idx >> 5;                 // 32 float4 per row
            int k4  = (idx & 31) << 2;
            float4 w = *(const float4*)(x_proj_w + ((size_t)s * 48 + row) * 512 + k0 + k4);
            *(float4*)&sWU[row * 132 + k4] = w;
        }
        __syncthreads();
        if (cl < 12) {
            for (int k = 0; k < 128; k += 4) {
                float4 xv = *(const float4*)&sXZ[cl * DI + k0 + k];
                float4 wa = *(const float4*)&sWU[(og * 3 + 0) * 132 + k];
                float4 wb = *(const float4*)&sWU[(og * 3 + 1) * 132 + k];
                float4 wc = *(const float4*)&sWU[(og * 3 + 2) * 132 + k];
                c0 = fma4(wa, xv, c0);
                c1 = fma4(wb, xv, c1);
                c2 = fma4(wc, xv, c2);
            }
        }
    }
    __syncthreads();   // sWU compute done; sXA(x_seq) dead -> reuse as x_dbl
    if (cl < 12) {
        sXA[cl * 48 + og * 3 + 0] = c0;
        sXA[cl * 48 + og * 3 + 1] = c1;
        sXA[cl * 48 + og * 3 + 2] = c2;
    }
    __syncthreads();

    // ---- phase E: dt_proj + softplus + scan + y, fused per d column ----
    // stage dt_proj_w as [512][17] (odd stride -> conflict-free scalar reads)
    #pragma unroll
    for (int j = 0; j < 8; ++j) {
        int idx = tid + (j << 8);               // float4 index 0..2047
        int row = idx >> 2;
        int c   = (idx & 3) << 2;
        float4 w = *(const float4*)(dt_proj_w + ((size_t)s * DI + row) * RR + c);
        sWU[row * 17 + c + 0] = w.x;
        sWU[row * 17 + c + 1] = w.y;
        sWU[row * 17 + c + 2] = w.z;
        sWU[row * 17 + c + 3] = w.w;
    }
    __syncthreads();

    for (int d = tid; d < DI; d += 256) {
        float dpb = dt_proj_b[s * DI + d];
        float wr[16];
        #pragma unroll
        for (int r = 0; r < 16; ++r) wr[r] = sWU[d * 17 + r];

        float dtv[LL];
        #pragma unroll
        for (int l = 0; l < LL; ++l) {
            float v = dpb;
            #pragma unroll
            for (int r = 0; r < 16; ++r) v = fmaf(sXA[l * 48 + r], wr[r], v);
            // softplus(v) = max(v,0) + log(1 + exp(-|v|))
            float e = __expf(-fabsf(v));
            dtv[l] = fmaxf(v, 0.0f) + __logf(1.0f + e);
        }

        float a[16];
        #pragma unroll
        for (int c = 0; c < 16; c += 4) {
            float4 al = *(const float4*)(A_log + ((size_t)s * DI + d) * 16 + c);
            a[c + 0] = -__expf(al.x);
            a[c + 1] = -__expf(al.y);
            a[c + 2] = -__expf(al.z);
            a[c + 3] = -__expf(al.w);
        }

        float h[16];
        #pragma unroll
        for (int n2 = 0; n2 < 16; ++n2) h[n2] = 0.0f;
        float xc_last = 0.0f;

        #pragma unroll
        for (int l = 0; l < LL; ++l) {
            float xcv = sXZ[l * DI + d];
            float dtl = dtv[l];
            float dx  = dtl * xcv;
            #pragma unroll
            for (int n2 = 0; n2 < 16; ++n2) {
                float Bn = sXA[l * 48 + 16 + n2];
                h[n2] = fmaf(__expf(dtl * a[n2]), h[n2], dx * Bn);
            }
            xc_last = xcv;
        }

        float y = 0.0f;
        #pragma unroll
        for (int n2 = 0; n2 < 16; ++n2) y = fmaf(h[n2], sXA[11 * 48 + 32 + n2], y);
        y = fmaf(Dw[s * DI + d], xc_last, y);
        float zv = sZ[d];
        y *= zv / (1.0f + __expf(-zv));         // * silu(z_last)
        ws_y[((size_t)(s * BN + bn)) * DI + d] = y;
    }
}

// ---------------------------------------------------------------------------
// K2: feats = Y @ out_proj_w^T per scale (M-tile 16, reuses weights across 16 seqs)
// ---------------------------------------------------------------------------
__global__ __launch_bounds__(256, 2)
void k2_outproj(const float* __restrict__ ws_y,
                const float* __restrict__ out_proj_w,
                float* __restrict__ ws_feats)
{
    const int mt  = blockIdx.x;      // 0..103
    const int s   = blockIdx.y;
    const int tid = threadIdx.x;
    const int bn0 = mt * 16;

    __shared__ float sY[16 * DI];        // 32 KB
    __shared__ float sW2[64 * 132];      // 33 KB

    #pragma unroll
    for (int j = 0; j < 8; ++j) {
        int idx = tid + (j << 8);        // float4 index 0..2047
        int row = idx >> 7;              // 128 float4 per row
        int k4  = (idx & 127) << 2;
        int bnr = bn0 + row;
        float4 v = make_float4(0.f, 0.f, 0.f, 0.f);
        if (bnr < BN) v = *(const float4*)(ws_y + ((size_t)(s * BN + bnr)) * DI + k4);
        *(float4*)&sY[row * DI + k4] = v;
    }

    const int eidx = tid & 63;
    const int mg   = tid >> 6;

    for (int e0 = 0; e0 < 256; e0 += 64) {
        float acc[4] = {0.f, 0.f, 0.f, 0.f};
        for (int k0 = 0; k0 < 512; k0 += 128) {
            __syncthreads();
            #pragma unroll
            for (int j = 0; j < 8; ++j) {
                int idx = tid + (j << 8);
                int row = idx >> 5;              // 32 float4 per row
                int k4  = (idx & 31) << 2;
                float4 w = *(const float4*)(out_proj_w + ((size_t)s * 256 + e0 + row) * 512 + k0 + k4);
                *(float4*)&sW2[row * 132 + k4] = w;
            }
            __syncthreads();
            for (int k = 0; k < 128; k += 4) {
                float4 w = *(const float4*)&sW2[eidx * 132 + k];
                #pragma unroll
                for (int i = 0; i < 4; ++i) {
                    float4 yv = *(const float4*)&sY[(mg * 4 + i) * DI + k0 + k];
                    acc[i] = fma4(w, yv, acc[i]);
                }
            }
        }
        #pragma unroll
        for (int i = 0; i < 4; ++i) {
            int bnr = bn0 + mg * 4 + i;
            if (bnr < BN) ws_feats[((size_t)s * BN + bnr) * 256 + e0 + eidx] = acc[i];
        }
    }
}

// ---------------------------------------------------------------------------
// K3: softmax over scales + blend
// ---------------------------------------------------------------------------
__global__ __launch_bounds__(256)
void k3_attn(const float* __restrict__ ws_feats,
             const float* __restrict__ attn_w,
             const float* __restrict__ attn_b,
             float* __restrict__ out)
{
    const int bn  = blockIdx.x;
    const int tid = threadIdx.x;

    float f0 = ws_feats[((size_t)0 * BN + bn) * 256 + tid];
    float f1 = ws_feats[((size_t)1 * BN + bn) * 256 + tid];
    float f2 = ws_feats[((size_t)2 * BN + bn) * 256 + tid];
    float aw = attn_w[tid];
    float p0 = f0 * aw, p1 = f1 * aw, p2 = f2 * aw;

    #pragma unroll
    for (int off = 32; off > 0; off >>= 1) {
        p0 += __shfl_down(p0, off);
        p1 += __shfl_down(p1, off);
        p2 += __shfl_down(p2, off);
    }

    __shared__ float red[3][4];
    int wv = tid >> 6, ln = tid & 63;
    if (ln == 0) { red[0][wv] = p0; red[1][wv] = p1; red[2][wv] = p2; }
    __syncthreads();

    float ab = attn_b[0];
    float s0 = red[0][0] + red[0][1] + red[0][2] + red[0][3] + ab;
    float s1 = red[1][0] + red[1][1] + red[1][2] + red[1][3] + ab;
    float s2 = red[2][0] + red[2][1] + red[2][2] + red[2][3] + ab;
    float m  = fmaxf(s0, fmaxf(s1, s2));
    float e0 = __expf(s0 - m), e1 = __expf(s1 - m), e2 = __expf(s2 - m);
    float inv = 1.0f / (e0 + e1 + e2);
    out[(size_t)bn * 256 + tid] = (e0 * f0 + e1 * f1 + e2 * f2) * inv;
}

extern "C" void kernel_launch(void* const* d_in, const int* in_sizes, int n_in,
                              void* d_out, int out_size, void* d_ws, size_t ws_size,
                              hipStream_t stream) {
    const float* x         = (const float*)d_in[0];
    const float* in_proj_w = (const float*)d_in[1];
    const float* conv_w    = (const float*)d_in[2];
    const float* conv_b    = (const float*)d_in[3];
    const float* x_proj_w  = (const float*)d_in[4];
    const float* dt_proj_w = (const float*)d_in[5];
    const float* dt_proj_b = (const float*)d_in[6];
    const float* A_log     = (const float*)d_in[7];
    const float* Dw        = (const float*)d_in[8];
    const float* out_proj_w= (const float*)d_in[9];
    const float* attn_w    = (const float*)d_in[10];
    const float* attn_b    = (const float*)d_in[11];
    float* outp = (float*)d_out;

    float* ws_y     = (float*)d_ws;                         // 3*1656*512 f32 = 10.2 MB
    float* ws_feats = ws_y + (size_t)S3 * BN * DI;          // 3*1656*256 f32 = 5.1 MB

    hipLaunchKernelGGL(k1_seq, dim3(BN, S3), dim3(256), 0, stream,
                       x, in_proj_w, conv_w, conv_b, x_proj_w,
                       dt_proj_w, dt_proj_b, A_log, Dw, ws_y);
    hipLaunchKernelGGL(k2_outproj, dim3((BN + 15) / 16, S3), dim3(256), 0, stream,
                       ws_y, out_proj_w, ws_feats);
    hipLaunchKernelGGL(k3_attn, dim3(BN), dim3(256), 0, stream,
                       ws_feats, attn_w, attn_b, outp);
}

// Round 2
// 1465.259 us; speedup vs baseline: 2.4709x; 2.4709x over previous
//
#include <hip/hip_runtime.h>
#include <hip/hip_bf16.h>

#define S3 3
#define BB 8
#define TT 48
#define NN 207
#define FF 256        // D_MODEL
#define DI 512        // D_INNER
#define DSN 16        // D_STATE
#define RR 16         // DT_RANK
#define LL 12
#define BN (BB*NN)    // 1656

__device__ __forceinline__ float fma4(float4 w, float4 v, float acc) {
    acc = fmaf(w.x, v.x, acc);
    acc = fmaf(w.y, v.y, acc);
    acc = fmaf(w.z, v.z, acc);
    acc = fmaf(w.w, v.w, acc);
    return acc;
}

// ---------------------------------------------------------------------------
// K1: per (scale, bn) sequence: in_proj -> conv+silu -> x_proj -> (dt_proj +
// scan fused) -> y   (y includes *silu(z_last) and D*xc_last)
// LDS total 59,392 B (< 64 KB) -> 2 blocks/CU
// ---------------------------------------------------------------------------
__global__ __launch_bounds__(256, 2)
void k1_seq(const float* __restrict__ x,
            const float* __restrict__ in_proj_w,
            const float* __restrict__ conv_w,
            const float* __restrict__ conv_b,
            const float* __restrict__ x_proj_w,
            const float* __restrict__ dt_proj_w,
            const float* __restrict__ dt_proj_b,
            const float* __restrict__ A_log,
            const float* __restrict__ Dw,
            float* __restrict__ ws_y)
{
    const int bn  = blockIdx.x;
    const int s   = blockIdx.y;
    const int tid = threadIdx.x;
    const int b   = bn / NN;
    const int n   = bn % NN;

    __shared__ float sXZ[LL * DI];      // 6144 f: xr then xc
    __shared__ float sWU[5200];         // A: [256][20]; C: [48][68]; E: [16][260]
    __shared__ float sXA[LL * FF];      // A: x_seq [12][256]; C+: x_dbl [12][48]
    __shared__ float sZ[DI];            // z at l=11

    // ---- load x_seq (gather the scale's 12 time steps) ----
    const int t0 = (s == 0) ? 36 : (s == 1) ? 24 : 0;
    const int st = (s == 0) ? 1  : (s == 1) ? 2  : 4;
    for (int i = tid; i < LL * FF / 4; i += 256) {   // 768 float4
        int l  = i >> 6;
        int k4 = (i & 63) << 2;
        float4 v = *(const float4*)(x + (((size_t)b * TT + (t0 + l * st)) * NN + n) * FF + k4);
        *(float4*)&sXA[l * FF + k4] = v;
    }

    // ---- phase A: xz = x_seq @ in_proj_w^T  (e-tile 256, k-tile 16) ----
    const int eidx = tid & 127;
    const int lg   = tid >> 7;

    for (int et = 0; et < 4; ++et) {
        const int  e0  = et << 8;
        const bool isz = (et >= 2);            // e >= 512: z half, only l=11
        float acc0[6] = {0.f,0.f,0.f,0.f,0.f,0.f};
        float acc1[6] = {0.f,0.f,0.f,0.f,0.f,0.f};

        for (int k0 = 0; k0 < 256; k0 += 16) {
            __syncthreads();
            // stage W[e0..e0+255][k0..k0+15], stride 20
            const float* wg = in_proj_w + ((size_t)s * 1024 + e0) * 256 + k0;
            #pragma unroll
            for (int j = 0; j < 4; ++j) {
                int idx = tid + (j << 8);       // float4 idx 0..1023
                int row = idx >> 2;             // 4 float4 per row
                int k4  = (idx & 3) << 2;
                float4 w = *(const float4*)(wg + (size_t)row * 256 + k4);
                *(float4*)&sWU[row * 20 + k4] = w;
            }
            __syncthreads();

            if (!isz) {
                #pragma unroll
                for (int k4 = 0; k4 < 16; k4 += 4) {
                    float4 w0 = *(const float4*)&sWU[eidx * 20 + k4];
                    float4 w1 = *(const float4*)&sWU[(eidx + 128) * 20 + k4];
                    #pragma unroll
                    for (int j = 0; j < 6; ++j) {
                        float4 xv = *(const float4*)&sXA[(lg * 6 + j) * FF + k0 + k4];
                        acc0[j] = fma4(w0, xv, acc0[j]);
                        acc1[j] = fma4(w1, xv, acc1[j]);
                    }
                }
            } else {
                #pragma unroll
                for (int k4 = 0; k4 < 16; k4 += 4) {
                    float4 w0 = *(const float4*)&sWU[eidx * 20 + k4];
                    float4 w1 = *(const float4*)&sWU[(eidx + 128) * 20 + k4];
                    float4 xv = *(const float4*)&sXA[11 * FF + k0 + k4];
                    acc0[5] = fma4(w0, xv, acc0[5]);
                    acc1[5] = fma4(w1, xv, acc1[5]);
                }
            }
        }

        if (!isz) {
            #pragma unroll
            for (int j = 0; j < 6; ++j) {
                sXZ[(lg * 6 + j) * DI + e0 + eidx]       = acc0[j];
                sXZ[(lg * 6 + j) * DI + e0 + eidx + 128] = acc1[j];
            }
        } else if (lg == 0) {
            sZ[e0 - 512 + eidx]       = acc0[5];
            sZ[e0 - 512 + eidx + 128] = acc1[5];
        }
    }
    __syncthreads();

    // ---- phase B: causal conv4 + silu, in place per column ----
    for (int d = tid; d < DI; d += 256) {
        float4 cw = *(const float4*)(conv_w + ((size_t)s * DI + d) * 4);
        float  cb = conv_b[s * DI + d];
        float r[LL];
        #pragma unroll
        for (int l = 0; l < LL; ++l) r[l] = sXZ[l * DI + d];
        #pragma unroll
        for (int l = 0; l < LL; ++l) {
            float v = cb;
            if (l >= 3) v = fmaf(r[l - 3], cw.x, v);
            if (l >= 2) v = fmaf(r[l - 2], cw.y, v);
            if (l >= 1) v = fmaf(r[l - 1], cw.z, v);
            v = fmaf(r[l], cw.w, v);
            v = v / (1.0f + __expf(-v));        // silu
            sXZ[l * DI + d] = v;
        }
    }
    __syncthreads();

    // ---- phase C: x_dbl = xc @ x_proj_w^T  (12 x 48, K=512, k-tile 64) ----
    const int cl = tid >> 4;      // 0..15 (valid < 12)
    const int og = tid & 15;      // 16 groups of 3 outputs
    float c0 = 0.f, c1 = 0.f, c2 = 0.f;
    for (int k0 = 0; k0 < 512; k0 += 64) {
        __syncthreads();
        // stage x_proj_w[0..47][k0..k0+63], stride 68
        #pragma unroll
        for (int j = 0; j < 3; ++j) {
            int idx = tid + (j << 8);           // float4 idx 0..767
            int row = idx >> 4;                 // 16 float4 per row
            int k4  = (idx & 15) << 2;
            float4 w = *(const float4*)(x_proj_w + ((size_t)s * 48 + row) * 512 + k0 + k4);
            *(float4*)&sWU[row * 68 + k4] = w;
        }
        __syncthreads();
        if (cl < 12) {
            for (int k = 0; k < 64; k += 4) {
                float4 xv = *(const float4*)&sXZ[cl * DI + k0 + k];
                float4 wa = *(const float4*)&sWU[(og * 3 + 0) * 68 + k];
                float4 wb = *(const float4*)&sWU[(og * 3 + 1) * 68 + k];
                float4 wc = *(const float4*)&sWU[(og * 3 + 2) * 68 + k];
                c0 = fma4(wa, xv, c0);
                c1 = fma4(wb, xv, c1);
                c2 = fma4(wc, xv, c2);
            }
        }
    }
    __syncthreads();   // sWU done; sXA (x_seq) dead -> reuse as x_dbl
    if (cl < 12) {
        sXA[cl * 48 + og * 3 + 0] = c0;
        sXA[cl * 48 + og * 3 + 1] = c1;
        sXA[cl * 48 + og * 3 + 2] = c2;
    }

    // ---- phase E: dt_proj + softplus + scan + y, d in two halves of 256 ----
    for (int dh = 0; dh < 2; ++dh) {
        __syncthreads();
        // stage dt_proj_w[s][dh*256 + dl][r] transposed -> sWU[r*260 + dl]
        #pragma unroll
        for (int j = 0; j < 4; ++j) {
            int idx = tid + (j << 8);           // 0..1023
            int dl  = idx >> 2;                 // 0..255
            int c   = idx & 3;
            float4 w = *(const float4*)(dt_proj_w + ((size_t)s * DI + dh * 256 + dl) * RR + (c << 2));
            sWU[((c << 2) + 0) * 260 + dl] = w.x;
            sWU[((c << 2) + 1) * 260 + dl] = w.y;
            sWU[((c << 2) + 2) * 260 + dl] = w.z;
            sWU[((c << 2) + 3) * 260 + dl] = w.w;
        }
        __syncthreads();

        const int d = dh * 256 + tid;
        float dpb = dt_proj_b[s * DI + d];
        float wr[16];
        #pragma unroll
        for (int r = 0; r < 16; ++r) wr[r] = sWU[r * 260 + tid];

        float a[16];
        #pragma unroll
        for (int c = 0; c < 16; c += 4) {
            float4 al = *(const float4*)(A_log + ((size_t)s * DI + d) * 16 + c);
            a[c + 0] = -__expf(al.x);
            a[c + 1] = -__expf(al.y);
            a[c + 2] = -__expf(al.z);
            a[c + 3] = -__expf(al.w);
        }

        float h[16];
        #pragma unroll
        for (int n2 = 0; n2 < 16; ++n2) h[n2] = 0.0f;
        float xc_last = 0.0f;

        #pragma unroll
        for (int l = 0; l < LL; ++l) {
            // dt inline
            float v = dpb;
            #pragma unroll
            for (int r = 0; r < 16; ++r) v = fmaf(sXA[l * 48 + r], wr[r], v);
            float e = __expf(-fabsf(v));
            float dtl = fmaxf(v, 0.0f) + __logf(1.0f + e);   // softplus

            float xcv = sXZ[l * DI + d];
            float dx  = dtl * xcv;
            #pragma unroll
            for (int n2 = 0; n2 < 16; ++n2) {
                float Bn = sXA[l * 48 + 16 + n2];
                h[n2] = fmaf(__expf(dtl * a[n2]), h[n2], dx * Bn);
            }
            xc_last = xcv;
        }

        float y = 0.0f;
        #pragma unroll
        for (int n2 = 0; n2 < 16; ++n2) y = fmaf(h[n2], sXA[11 * 48 + 32 + n2], y);
        y = fmaf(Dw[s * DI + d], xc_last, y);
        float zv = sZ[d];
        y *= zv / (1.0f + __expf(-zv));         // * silu(z_last)
        ws_y[((size_t)(s * BN + bn)) * DI + d] = y;
    }
}

// ---------------------------------------------------------------------------
// K_WT: transpose out_proj_w [3][256][512] -> wT [3][512][256]
// ---------------------------------------------------------------------------
__global__ __launch_bounds__(256)
void k_wt(const float* __restrict__ w, float* __restrict__ wT)
{
    int idx = blockIdx.x * 256 + threadIdx.x;   // over 3*512*256, e fastest
    int e = idx & 255;
    int k = (idx >> 8) & 511;
    int s = idx >> 17;
    wT[idx] = w[((size_t)s * 256 + e) * 512 + k];
}

// ---------------------------------------------------------------------------
// K2: per bn: feats[s][e] = y[s] . wT[s][:,e]; then attn softmax blend -> out
// ---------------------------------------------------------------------------
__global__ __launch_bounds__(256)
void k2_fused(const float* __restrict__ ws_y,
              const float* __restrict__ wT,
              const float* __restrict__ attn_w,
              const float* __restrict__ attn_b,
              float* __restrict__ out)
{
    const int bn  = blockIdx.x;
    const int tid = threadIdx.x;

    __shared__ float sy[3 * DI];        // 6 KB
    __shared__ float sP[4][3 * 256];    // per-wave partials, 12 KB
    __shared__ float red[3][4];

    for (int i = tid; i < 384; i += 256) {          // 3*512/4 float4
        int ss = i >> 7;
        int k4 = (i & 127) << 2;
        *(float4*)&sy[ss * DI + k4] =
            *(const float4*)&ws_y[((size_t)ss * BN + bn) * DI + k4];
    }
    __syncthreads();

    const int kk = tid >> 6;            // wave id 0..3 = k-slice
    const int eq = (tid & 63) << 2;     // e base (float4 along e)

    #pragma unroll
    for (int ss = 0; ss < 3; ++ss) {
        float4 acc = make_float4(0.f, 0.f, 0.f, 0.f);
        for (int k = kk; k < DI; k += 4) {
            float  yv = sy[ss * DI + k];                          // wave-uniform broadcast
            float4 w  = *(const float4*)&wT[((size_t)ss * DI + k) * 256 + eq];
            acc.x = fmaf(w.x, yv, acc.x);
            acc.y = fmaf(w.y, yv, acc.y);
            acc.z = fmaf(w.z, yv, acc.z);
            acc.w = fmaf(w.w, yv, acc.w);
        }
        *(float4*)&sP[kk][ss * 256 + eq] = acc;
    }
    __syncthreads();

    // thread owns e = tid
    float f0 = sP[0][0*256+tid] + sP[1][0*256+tid] + sP[2][0*256+tid] + sP[3][0*256+tid];
    float f1 = sP[0][1*256+tid] + sP[1][1*256+tid] + sP[2][1*256+tid] + sP[3][1*256+tid];
    float f2 = sP[0][2*256+tid] + sP[1][2*256+tid] + sP[2][2*256+tid] + sP[3][2*256+tid];

    float aw = attn_w[tid];
    float p0 = f0 * aw, p1 = f1 * aw, p2 = f2 * aw;
    #pragma unroll
    for (int off = 32; off > 0; off >>= 1) {
        p0 += __shfl_down(p0, off);
        p1 += __shfl_down(p1, off);
        p2 += __shfl_down(p2, off);
    }
    int wv = tid >> 6, ln = tid & 63;
    if (ln == 0) { red[0][wv] = p0; red[1][wv] = p1; red[2][wv] = p2; }
    __syncthreads();

    float ab = attn_b[0];
    float s0 = red[0][0] + red[0][1] + red[0][2] + red[0][3] + ab;
    float s1 = red[1][0] + red[1][1] + red[1][2] + red[1][3] + ab;
    float s2 = red[2][0] + red[2][1] + red[2][2] + red[2][3] + ab;
    float m  = fmaxf(s0, fmaxf(s1, s2));
    float e0 = __expf(s0 - m), e1 = __expf(s1 - m), e2 = __expf(s2 - m);
    float inv = 1.0f / (e0 + e1 + e2);
    out[(size_t)bn * 256 + tid] = (e0 * f0 + e1 * f1 + e2 * f2) * inv;
}

extern "C" void kernel_launch(void* const* d_in, const int* in_sizes, int n_in,
                              void* d_out, int out_size, void* d_ws, size_t ws_size,
                              hipStream_t stream) {
    const float* x         = (const float*)d_in[0];
    const float* in_proj_w = (const float*)d_in[1];
    const float* conv_w    = (const float*)d_in[2];
    const float* conv_b    = (const float*)d_in[3];
    const float* x_proj_w  = (const float*)d_in[4];
    const float* dt_proj_w = (const float*)d_in[5];
    const float* dt_proj_b = (const float*)d_in[6];
    const float* A_log     = (const float*)d_in[7];
    const float* Dw        = (const float*)d_in[8];
    const float* out_proj_w= (const float*)d_in[9];
    const float* attn_w    = (const float*)d_in[10];
    const float* attn_b    = (const float*)d_in[11];
    float* outp = (float*)d_out;

    float* ws_y = (float*)d_ws;                         // 3*1656*512 f32 = 10.2 MB
    float* wT   = ws_y + (size_t)S3 * BN * DI;          // 3*512*256 f32 = 1.5 MB

    hipLaunchKernelGGL(k_wt, dim3((S3 * 512 * 256) / 256), dim3(256), 0, stream,
                       out_proj_w, wT);
    hipLaunchKernelGGL(k1_seq, dim3(BN, S3), dim3(256), 0, stream,
                       x, in_proj_w, conv_w, conv_b, x_proj_w,
                       dt_proj_w, dt_proj_b, A_log, Dw, ws_y);
    hipLaunchKernelGGL(k2_fused, dim3(BN), dim3(256), 0, stream,
                       ws_y, wT, attn_w, attn_b, outp);
}